// Round 2
// baseline (370.932 us; speedup 1.0000x reference)
//
#include <hip/hip_runtime.h>

#define NB 64
#define NS 4096
#define NC 256
#define KTOP 8
#define G 16               // segments along S -> grid 16*64 = 1024 blocks = 4/CU, tail-free
#define ROWS (NS / G)      // 256 rows per segment
#define WROWS (ROWS / 4)   // 64 rows per wave

// Branchless insert of v into sorted-descending top-8 list (drops smallest).
// Serial dep chain is only the 8 fmin's (t[j] updates are off critical path).
__device__ __forceinline__ void ins8(float (&t)[KTOP], float v) {
#pragma unroll
  for (int j = 0; j < KTOP; ++j) {
    float a = t[j];
    t[j] = fmaxf(a, v);
    v = fminf(a, v);
  }
}

// Kernel 1: per (segment, batch) block, per-channel top-8 over ROWS rows.
// Lane l owns channels 4l..4l+3 (float4 loads, fully coalesced: 1 KB/wave-load).
// Wave w owns rows w*WROWS..+WROWS. Cross-wave merge via LDS in two half
// passes (publishes 2 of 4 channel-sublanes at a time -> 17.4 KB pub buffer),
// results staged in lds_out so the global write is coalesced across c.
__global__ __launch_bounds__(256, 4) void kmax_partial(
    const float* __restrict__ x, float* __restrict__ ws) {
  const int g = blockIdx.x, b = blockIdx.y;
  const int tid = threadIdx.x;
  const int w = tid >> 6, l = tid & 63;

  float t[4][KTOP];
#pragma unroll
  for (int q = 0; q < 4; ++q)
#pragma unroll
    for (int j = 0; j < KTOP; ++j) t[q][j] = -INFINITY;

  const int s0 = g * ROWS + w * WROWS;
  const float4* xp =
      reinterpret_cast<const float4*>(x) + (size_t)(b * NS + s0) * (NC / 4) + l;
#pragma unroll 4
  for (int i = 0; i < WROWS; ++i) {
    float4 v = xp[(size_t)i * (NC / 4)];
    ins8(t[0], v.x);
    ins8(t[1], v.y);
    ins8(t[2], v.z);
    ins8(t[3], v.w);
  }

  __shared__ float lds_pub[256][2 * KTOP + 1];  // 17.4 KB, +1 pad
  __shared__ float lds_out[NC][KTOP + 1];       // 9.2 KB, +1 pad

  // Two-half merge: half h covers channel sublanes q = 2h, 2h+1.
#pragma unroll
  for (int h = 0; h < 2; ++h) {
#pragma unroll
    for (int q = 0; q < 2; ++q)
#pragma unroll
      for (int j = 0; j < KTOP; ++j)
        lds_pub[tid][q * KTOP + j] = t[2 * h + q][j];
    __syncthreads();
    if (tid < 128) {
      const int c4 = tid >> 1, qs = tid & 1;  // merge lane c4, sublane 2h+qs
      float m[KTOP];
#pragma unroll
      for (int j = 0; j < KTOP; ++j) m[j] = -INFINITY;
#pragma unroll
      for (int wv = 0; wv < 4; ++wv)
#pragma unroll
        for (int j = 0; j < KTOP; ++j)
          ins8(m, lds_pub[wv * 64 + c4][qs * KTOP + j]);
      const int c = 4 * c4 + 2 * h + qs;
#pragma unroll
      for (int j = 0; j < KTOP; ++j) lds_out[c][j] = m[j];
    }
    __syncthreads();
  }

  // Coalesced write of the block's 256 per-channel lists. ws layout: [b][g][j][c]
  const size_t base = ((size_t)(b * G + g) * KTOP) * NC + tid;
#pragma unroll
  for (int j = 0; j < KTOP; ++j) ws[base + (size_t)j * NC] = lds_out[tid][j];
}

// Kernel 2a: merge 4 segment-lists -> 1 per (b, quarter, c). Coalesced across c.
__global__ __launch_bounds__(256, 4) void kmax_merge1(
    const float* __restrict__ ws, float* __restrict__ ws2) {
  const int gq = blockIdx.x, b = blockIdx.y, c = threadIdx.x;
  float m[KTOP];
#pragma unroll
  for (int j = 0; j < KTOP; ++j) m[j] = -INFINITY;
  const float* src = ws + ((size_t)(b * G + gq * 4) * KTOP) * NC + c;
#pragma unroll
  for (int gg = 0; gg < 4; ++gg)
#pragma unroll
    for (int j = 0; j < KTOP; ++j)
      ins8(m, src[(size_t)(gg * KTOP + j) * NC]);
  float* dst = ws2 + ((size_t)(b * 4 + gq) * KTOP) * NC + c;
#pragma unroll
  for (int j = 0; j < KTOP; ++j) dst[(size_t)j * NC] = m[j];
}

// Kernel 2b: merge the 4 quarter-lists -> final top-8, sorted descending.
__global__ __launch_bounds__(256, 4) void kmax_merge2(
    const float* __restrict__ ws2, float* __restrict__ out) {
  const int b = blockIdx.x, c = threadIdx.x;
  float m[KTOP];
#pragma unroll
  for (int j = 0; j < KTOP; ++j) m[j] = -INFINITY;
  const float* src = ws2 + ((size_t)(b * 4) * KTOP) * NC + c;
#pragma unroll
  for (int p = 0; p < 4; ++p)
#pragma unroll
    for (int j = 0; j < KTOP; ++j)
      ins8(m, src[(size_t)(p * KTOP + j) * NC]);
  // out layout: [b][k][c]
  float* dst = out + ((size_t)b * KTOP) * NC + c;
#pragma unroll
  for (int j = 0; j < KTOP; ++j) dst[(size_t)j * NC] = m[j];
}

extern "C" void kernel_launch(void* const* d_in, const int* in_sizes, int n_in,
                              void* d_out, int out_size, void* d_ws,
                              size_t ws_size, hipStream_t stream) {
  const float* x = (const float*)d_in[0];
  float* ws1 = (float*)d_ws;                      // 64*16*8*256 floats (8.4 MB)
  float* ws2 = ws1 + (size_t)NB * G * KTOP * NC;  // 64*4*8*256 floats (2.1 MB)
  float* out = (float*)d_out;

  kmax_partial<<<dim3(G, NB), 256, 0, stream>>>(x, ws1);
  kmax_merge1<<<dim3(4, NB), 256, 0, stream>>>(ws1, ws2);
  kmax_merge2<<<dim3(NB), 256, 0, stream>>>(ws2, out);
}